// Round 6
// baseline (111.318 us; speedup 1.0000x reference)
//
#include <hip/hip_runtime.h>

// EdgeConv (B=2, N=8192, C=64, K=20, OUT=64):
//  proj    -> per-point 64->64 projections (8-way split over mat x out-quarter;
//             builds combined weights (w1-w2),(w2+w3) in LDS from w directly;
//             by==0 blocks also pack cpack = (x,y,z,|c|^2))
//  knnfeat -> fused, 512 threads (8 waves x 8 queries): LDS-resident candidates.
//             pass1: lane bin-minima of d~ = |c|^2 - 2 q.c (3 fma) ->
//                    tau >= d~_(20) via 24-step float bisection (ballot count)
//             pass2: ballot-compact (<=64) candidates with d~ <= tau
//             exact fp64 rank select (readlane broadcast, ties -> lower idx)
//             feat: edge features + gathered projections + BN/leaky/max,
//                   swizzled LDS transpose stage -> coalesced float4 out.
//  QW=8: each ds_read_b128 of a candidate feeds 8 queries (32 VALU) -- the
//  per-CU LDS pipe (which bound the QW=4 version) is now fully hidden.

#define NPTS 8192
#define NBATCH 2
#define NQ (NBATCH * NPTS)
#define CH 64
#define KNN 20
#define EDIM 197
#define QW 8             // queries per wave
#define KWAVES 8         // waves per block (512 threads)
#define QB (QW * KWAVES) // 64 queries per block
#define CAPC 64          // collected-candidate capacity (mean ~24)

__device__ __forceinline__ float wsum(float v) {
  v += __shfl_xor(v, 1, 64);
  v += __shfl_xor(v, 2, 64);
  v += __shfl_xor(v, 4, 64);
  v += __shfl_xor(v, 8, 64);
  v += __shfl_xor(v, 16, 64);
  v += __shfl_xor(v, 32, 64);
  return v;
}

// monotone-shifted distance surrogate: d~ = |c|^2 - 2 q.c  (= d^2 - |q|^2 exact)
// identical fmaf chain in both passes -> bitwise-consistent
__device__ __forceinline__ float dtilde(float m2x, float m2y, float m2z, float4 c) {
  return fmaf(m2x, c.x, fmaf(m2y, c.y, fmaf(m2z, c.z, c.w)));
}

// exact-enough fp64 true distance (fp32 diffs exact in fp64, squares exact)
__device__ __forceinline__ double d2d(float qx, float qy, float qz, float4 c) {
  double dx = (double)qx - (double)c.x;
  double dy = (double)qy - (double)c.y;
  double dz = (double)qz - (double)c.z;
  return dx * dx + dy * dy + dz * dz;
}

__device__ __forceinline__ float bcastf(float v, int l) {
  return __int_as_float(__builtin_amdgcn_readlane(__float_as_int(v), l));
}

// blockIdx.y in [0,8): mat = by>>2, output-quarter = by&3 (16 channels each).
// by==0 blocks additionally pack cpack (xyz + |c|^2).
__global__ __launch_bounds__(256) void proj_kernel(const float* __restrict__ x,
                                                   const float* __restrict__ w,
                                                   float4* __restrict__ cpack,
                                                   float* __restrict__ projc,
                                                   float* __restrict__ projn) {
  __shared__ float wl[CH * 16];
  int by = blockIdx.y;
  int mat = by >> 2, oq = by & 3;
  for (int i = threadIdx.x; i < CH * 16; i += 256) {
    int c = i >> 4, oo = i & 15;
    int o = oq * 16 + oo;
    float w1 = w[o * EDIM + c];
    float w2 = w[o * EDIM + 64 + c];
    float w3 = w[o * EDIM + 128 + c];
    wl[i] = mat ? (w2 + w3) : (w1 - w2);
  }
  __syncthreads();
  int p = blockIdx.x * 256 + threadIdx.x;
  int b = p >> 13, n = p & (NPTS - 1);
  const float* xb = x + (size_t)b * CH * NPTS + n;
  float acc[16];
#pragma unroll
  for (int o = 0; o < 16; ++o) acc[o] = 0.f;
#pragma unroll 4
  for (int c = 0; c < CH; ++c) {
    float xv = xb[(size_t)c * NPTS]; // coalesced across threads
    const float4* wr = (const float4*)(wl + c * 16); // uniform -> broadcast
#pragma unroll
    for (int o4 = 0; o4 < 4; ++o4) {
      float4 wv = wr[o4];
      acc[o4 * 4 + 0] = fmaf(wv.x, xv, acc[o4 * 4 + 0]);
      acc[o4 * 4 + 1] = fmaf(wv.y, xv, acc[o4 * 4 + 1]);
      acc[o4 * 4 + 2] = fmaf(wv.z, xv, acc[o4 * 4 + 2]);
      acc[o4 * 4 + 3] = fmaf(wv.w, xv, acc[o4 * 4 + 3]);
    }
  }
  float* dst = (mat ? projn : projc) + (size_t)p * 64 + oq * 16;
#pragma unroll
  for (int o4 = 0; o4 < 4; ++o4)
    ((float4*)dst)[o4] = make_float4(acc[o4 * 4 + 0], acc[o4 * 4 + 1],
                                     acc[o4 * 4 + 2], acc[o4 * 4 + 3]);
  if (by == 0) {
    float cx = xb[0], cy = xb[(size_t)NPTS], cz = xb[(size_t)2 * NPTS];
    cpack[p] = make_float4(cx, cy, cz, fmaf(cx, cx, fmaf(cy, cy, cz * cz)));
  }
}

__global__ __launch_bounds__(512, 2) void knnfeat_kernel(const float4* __restrict__ cpack,
                                                         const float* __restrict__ projc,
                                                         const float* __restrict__ projn,
                                                         const float* __restrict__ w,
                                                         const float* __restrict__ gamma,
                                                         const float* __restrict__ beta,
                                                         const float* __restrict__ mean,
                                                         const float* __restrict__ var,
                                                         float* __restrict__ out) {
  __shared__ float4 t4[NPTS];             // 128 KB, live for whole kernel
  __shared__ int lidx[KWAVES][QW][CAPC];  // 16 KB; reused as zbuf (per-wave rows)
  __shared__ int nsel[KWAVES][QW][KNN];   // 5 KB
  int tid = threadIdx.x;
  int lane = tid & 63;
  int wq = tid >> 6;            // wave 0..7
  int blk = blockIdx.x;         // 256 blocks (1 per CU)
  int bb = blk >> 7;            // batch
  int q0 = blk * QB + wq * QW;  // this wave's 8 queries
  const float4* cb = cpack + bb * NPTS;

  for (int i = tid; i < NPTS; i += 512) t4[i] = cb[i];
  float qx[QW], qy[QW], qz[QW], m2x[QW], m2y[QW], m2z[QW];
#pragma unroll
  for (int qi = 0; qi < QW; ++qi) {
    float4 qp = cpack[q0 + qi];
    qx[qi] = qp.x; qy[qi] = qp.y; qz[qi] = qp.z;
    m2x[qi] = -2.f * qp.x; m2y[qi] = -2.f * qp.y; m2z[qi] = -2.f * qp.z;
  }
  __syncthreads();

  // ---- pass 1: per-lane bin minima of d~ (128 candidates per lane, 8 queries)
  float m[QW];
#pragma unroll
  for (int qi = 0; qi < QW; ++qi) m[qi] = 3.0e38f;
#pragma unroll 4
  for (int i = 0; i < NPTS / 64; ++i) {
    float4 c = t4[lane + i * 64];
#pragma unroll
    for (int qi = 0; qi < QW; ++qi)
      m[qi] = fminf(m[qi], dtilde(m2x[qi], m2y[qi], m2z[qi], c));
  }
  // tau >= 20th-smallest lane-min (>= global d~_(20)) via float bisection.
  // Invariant: count(m <= hi) >= KNN. |d~| <= |c|^2+2|q||c| < 100 << 256.
  float lo[QW], hi[QW];
#pragma unroll
  for (int qi = 0; qi < QW; ++qi) { lo[qi] = -256.f; hi[qi] = 256.f; }
#pragma unroll 1
  for (int it = 0; it < 24; ++it) {
#pragma unroll
    for (int qi = 0; qi < QW; ++qi) {
      float mid = (lo[qi] + hi[qi]) * 0.5f;
      int c = (int)__popcll(__ballot(m[qi] <= mid));
      if (c >= KNN) hi[qi] = mid; else lo[qi] = mid;
    }
  }

  // ---- pass 2: ballot-compact candidates with d~ <= tau (~24 expected/query)
  int cnt[QW];
#pragma unroll
  for (int qi = 0; qi < QW; ++qi) cnt[qi] = 0;
  unsigned long long lmlt = (1ull << lane) - 1ull;
#pragma unroll 2
  for (int i = 0; i < NPTS / 64; ++i) {
    float4 c = t4[lane + i * 64];
#pragma unroll
    for (int qi = 0; qi < QW; ++qi) {
      bool pr = dtilde(m2x[qi], m2y[qi], m2z[qi], c) <= hi[qi];
      unsigned long long mk = __ballot(pr);
      if (mk) { // SALU-cheap bookkeeping, branch skipped ~81% of iters
        int ofs = cnt[qi] + (int)__popcll(mk & lmlt);
        if (pr && ofs < CAPC) lidx[wq][qi][ofs] = lane + i * 64;
        cnt[qi] += (int)__popcll(mk);
      }
    }
  }

  // ---- exact fp64 rank select: one candidate per lane, readlane broadcast
  double dd[QW]; int ii[QW]; int cC[QW];
#pragma unroll
  for (int qi = 0; qi < QW; ++qi) {
    cC[qi] = min(cnt[qi], CAPC);
    dd[qi] = 1e300; ii[qi] = -1;
    if (lane < cC[qi]) {
      int id = lidx[wq][qi][lane];
      dd[qi] = d2d(qx[qi], qy[qi], qz[qi], t4[id]);
      ii[qi] = id;
    }
  }
#pragma unroll
  for (int qi = 0; qi < QW; ++qi) {
    int xlo = __double2loint(dd[qi]), xhi = __double2hiint(dd[qi]);
    int r = 0;
#pragma unroll 1
    for (int j = 0; j < cC[qi]; ++j) {
      double dj = __hiloint2double(__builtin_amdgcn_readlane(xhi, j),
                                   __builtin_amdgcn_readlane(xlo, j));
      int idj = __builtin_amdgcn_readlane(ii[qi], j);
      r += (dj < dd[qi]) || (dj == dd[qi] && idj < ii[qi]);
    }
    if (ii[qi] >= 0 && r < KNN) nsel[wq][qi][r] = ii[qi];
  }

  // ---- fused feature + conv + BN/leaky + max-over-k epilogue
  float* zbuf = (float*)&lidx[0][0][0]; // per-wave region == own dead lidx rows
  float wd  = w[lane * EDIM + 192];
  float wld = w[lane * EDIM + 193];
  float wrh = w[lane * EDIM + 194];
  float wdv = w[lane * EDIM + 195];
  float wa  = w[lane * EDIM + 196];
  float sc = gamma[lane] / sqrtf(var[lane] + 1e-5f);
  float muv = mean[lane], bt = beta[lane];
#pragma unroll 2
  for (int qi = 0; qi < QW; ++qi) {
    int gq = q0 + qi;
    int jj = nsel[wq][qi][lane < KNN ? lane : 0] & (NPTS - 1);
    float4 nb = t4[jj];
    float vx = nb.x - qx[qi], vy = nb.y - qy[qi], vz = nb.z - qz[qi];
    float dist = sqrtf(fmaf(vx, vx, fmaf(vy, vy, vz * vz)));
    float inv = 1.f / (dist + 1e-6f);
    float vnx = vx * inv, vny = vy * inv, vnz = vz * inv;
    float msk = (lane < KNN) ? 1.f : 0.f;
    float sd = wsum(dist * msk);
    float szn = wsum(nb.z * msk);
    float sx = wsum(vnx * msk);
    float sy = wsum(vny * msk);
    float s3 = wsum(vnz * msk);
    float ld = sd * (1.f / KNN);
    float rh = qz[qi] - szn * (1.f / KNN);
    float dev = dist - ld;
    float dvs = wsum(dev * dev * msk);
    float dv = dvs * (1.f / (KNN - 1));
    float mdx = sx * (1.f / KNN), mdy = sy * (1.f / KNN), mdz = s3 * (1.f / KNN);
    float mnorm = sqrtf(fmaf(mdx, mdx, fmaf(mdy, mdy, mdz * mdz)));
    float rinv = 1.f / (mnorm + 1e-6f);
    mdx *= rinv; mdy *= rinv; mdz *= rinv;
    float cosv = vnx * mdx + vny * mdy + vnz * mdz;
    float angle = 1.f - fabsf(cosv);
    float base = projc[(size_t)gq * 64 + lane] + ld * wld + rh * wrh + dv * wdv;
    float zmax = -3.0e38f, zmin = 3.0e38f;
#pragma unroll
    for (int kk = 0; kk < KNN; ++kk) {
      float dk = bcastf(dist, kk);
      float ak = bcastf(angle, kk);
      int jk = __builtin_amdgcn_readlane(jj, kk);
      float z = base + projn[(size_t)(bb * NPTS + jk) * 64 + lane] + dk * wd + ak * wa;
      zmax = fmaxf(zmax, z);
      zmin = fminf(zmin, z);
    }
    float M = (sc >= 0.f) ? zmax : zmin; // BN scale sign-aware (monotone epilogue)
    float yv = (M - muv) * sc + bt;
    yv = (yv >= 0.f) ? yv : 0.2f * yv;
    int qcol = wq * QW + qi;
    zbuf[qcol * 64 + ((lane + qcol) & 63)] = yv; // swizzled: conflict-free both ways
  }
  __syncthreads();
  // cooperative transpose writeout: out[b][o][n0..n0+63], 8 floats per thread
  {
    int o = tid >> 3, g = tid & 7;
    int n0 = (blk & 127) * 64;
    int q8 = g * 8;
    float4 v0, v1;
    v0.x = zbuf[(q8 + 0) * 64 + ((o + q8 + 0) & 63)];
    v0.y = zbuf[(q8 + 1) * 64 + ((o + q8 + 1) & 63)];
    v0.z = zbuf[(q8 + 2) * 64 + ((o + q8 + 2) & 63)];
    v0.w = zbuf[(q8 + 3) * 64 + ((o + q8 + 3) & 63)];
    v1.x = zbuf[(q8 + 4) * 64 + ((o + q8 + 4) & 63)];
    v1.y = zbuf[(q8 + 5) * 64 + ((o + q8 + 5) & 63)];
    v1.z = zbuf[(q8 + 6) * 64 + ((o + q8 + 6) & 63)];
    v1.w = zbuf[(q8 + 7) * 64 + ((o + q8 + 7) & 63)];
    float* op = out + (size_t)bb * CH * NPTS + (size_t)o * NPTS + n0 + q8;
    *(float4*)op = v0;
    *(float4*)(op + 4) = v1;
  }
}

extern "C" void kernel_launch(void* const* d_in, const int* in_sizes, int n_in,
                              void* d_out, int out_size, void* d_ws, size_t ws_size,
                              hipStream_t stream) {
  const float* x = (const float*)d_in[0];
  const float* w = (const float*)d_in[1];
  const float* gamma = (const float*)d_in[2];
  const float* beta = (const float*)d_in[3];
  const float* mean = (const float*)d_in[4];
  const float* var = (const float*)d_in[5];
  float* out = (float*)d_out;

  // workspace layout
  const size_t OFF_CPACK = 0;                 // 262144 B
  const size_t OFF_PROJC = 262144;            // 4 MiB
  const size_t OFF_PROJN = 262144 + 4194304;  // 4 MiB
  const size_t NEED = 262144 + 8388608;
  if (ws_size < NEED) return;

  char* ws = (char*)d_ws;
  float4* cpack = (float4*)(ws + OFF_CPACK);
  float* projc = (float*)(ws + OFF_PROJC);
  float* projn = (float*)(ws + OFF_PROJN);

  proj_kernel<<<dim3(64, 8), 256, 0, stream>>>(x, w, cpack, projc, projn);
  knnfeat_kernel<<<256, 512, 0, stream>>>(cpack, projc, projn, w,
                                          gamma, beta, mean, var, out);
}

// Round 7
// 94.742 us; speedup vs baseline: 1.1750x; 1.1750x over previous
//
#include <hip/hip_runtime.h>

// EdgeConv (B=2, N=8192, C=64, K=20, OUT=64):
//  proj    -> per-point 64->64 projections (8-way split over mat x out-quarter;
//             builds combined weights (w1-w2),(w2+w3) in LDS from w directly;
//             by==0 blocks also pack cpack = (x,y,z,|c|^2))
//  knnfeat -> fused, 1024 threads (16 waves x 4 queries; 4 waves/SIMD -- the
//             verified occupancy sweet spot). LDS candidate tile in pair-SoA
//             layout; scan core uses v_pk_fma_f32 (2 candidates/instr).
//             pass1: lane bin-minima of d~ = |c|^2 - 2 q.c ->
//                    tau >= d~_(20) via 24-step float bisection (ballot count)
//             pass2: ballot-compact (<=64) candidates with d~ <= tau
//             exact fp64 rank select (readlane broadcast, ties -> lower idx)
//             feat: edge features + gathered projections + BN/leaky/max,
//                   swizzled LDS transpose stage -> coalesced float4 out.

#define NPTS 8192
#define NBATCH 2
#define NQ (NBATCH * NPTS)
#define CH 64
#define KNN 20
#define EDIM 197
#define QW 4             // queries per wave
#define KWAVES 16        // waves per block (1024 threads)
#define QB (QW * KWAVES) // 64 queries per block
#define CAPC 64          // collected-candidate capacity (mean ~24)

typedef float v2f __attribute__((ext_vector_type(2)));

// packed dual fp32 FMA: each half is an IEEE fma, bitwise == fmaf chain
__device__ __forceinline__ v2f pk_fma(v2f a, v2f b, v2f c) {
  v2f d;
  asm("v_pk_fma_f32 %0, %1, %2, %3" : "=v"(d) : "v"(a), "v"(b), "v"(c));
  return d;
}

__device__ __forceinline__ float wsum(float v) {
  v += __shfl_xor(v, 1, 64);
  v += __shfl_xor(v, 2, 64);
  v += __shfl_xor(v, 4, 64);
  v += __shfl_xor(v, 8, 64);
  v += __shfl_xor(v, 16, 64);
  v += __shfl_xor(v, 32, 64);
  return v;
}

// d~ pair for candidates (2j, 2j+1):
// A=(x0,x1,y0,y1), B=(z0,z1,w0,w1); d~ = fma(m2x,x, fma(m2y,y, fma(m2z,z,w)))
__device__ __forceinline__ v2f dtilde2(v2f m2x, v2f m2y, v2f m2z,
                                       float4 A, float4 Bv) {
  v2f xx = {A.x, A.y}, yy = {A.z, A.w}, zz = {Bv.x, Bv.y}, ww = {Bv.z, Bv.w};
  return pk_fma(m2x, xx, pk_fma(m2y, yy, pk_fma(m2z, zz, ww)));
}

// exact-enough fp64 true distance (fp32 diffs exact in fp64, squares exact)
__device__ __forceinline__ double d2d(float qx, float qy, float qz,
                                      float cx, float cy, float cz) {
  double dx = (double)qx - (double)cx;
  double dy = (double)qy - (double)cy;
  double dz = (double)qz - (double)cz;
  return dx * dx + dy * dy + dz * dz;
}

__device__ __forceinline__ float bcastf(float v, int l) {
  return __int_as_float(__builtin_amdgcn_readlane(__float_as_int(v), l));
}

// blockIdx.y in [0,8): mat = by>>2, output-quarter = by&3 (16 channels each).
// by==0 blocks additionally pack cpack (xyz + |c|^2).
__global__ __launch_bounds__(256) void proj_kernel(const float* __restrict__ x,
                                                   const float* __restrict__ w,
                                                   float4* __restrict__ cpack,
                                                   float* __restrict__ projc,
                                                   float* __restrict__ projn) {
  __shared__ float wl[CH * 16];
  int by = blockIdx.y;
  int mat = by >> 2, oq = by & 3;
  for (int i = threadIdx.x; i < CH * 16; i += 256) {
    int c = i >> 4, oo = i & 15;
    int o = oq * 16 + oo;
    float w1 = w[o * EDIM + c];
    float w2 = w[o * EDIM + 64 + c];
    float w3 = w[o * EDIM + 128 + c];
    wl[i] = mat ? (w2 + w3) : (w1 - w2);
  }
  __syncthreads();
  int p = blockIdx.x * 256 + threadIdx.x;
  int b = p >> 13, n = p & (NPTS - 1);
  const float* xb = x + (size_t)b * CH * NPTS + n;
  float acc[16];
#pragma unroll
  for (int o = 0; o < 16; ++o) acc[o] = 0.f;
#pragma unroll 4
  for (int c = 0; c < CH; ++c) {
    float xv = xb[(size_t)c * NPTS]; // coalesced across threads
    const float4* wr = (const float4*)(wl + c * 16); // uniform -> broadcast
#pragma unroll
    for (int o4 = 0; o4 < 4; ++o4) {
      float4 wv = wr[o4];
      acc[o4 * 4 + 0] = fmaf(wv.x, xv, acc[o4 * 4 + 0]);
      acc[o4 * 4 + 1] = fmaf(wv.y, xv, acc[o4 * 4 + 1]);
      acc[o4 * 4 + 2] = fmaf(wv.z, xv, acc[o4 * 4 + 2]);
      acc[o4 * 4 + 3] = fmaf(wv.w, xv, acc[o4 * 4 + 3]);
    }
  }
  float* dst = (mat ? projn : projc) + (size_t)p * 64 + oq * 16;
#pragma unroll
  for (int o4 = 0; o4 < 4; ++o4)
    ((float4*)dst)[o4] = make_float4(acc[o4 * 4 + 0], acc[o4 * 4 + 1],
                                     acc[o4 * 4 + 2], acc[o4 * 4 + 3]);
  if (by == 0) {
    float cx = xb[0], cy = xb[(size_t)NPTS], cz = xb[(size_t)2 * NPTS];
    cpack[p] = make_float4(cx, cy, cz, fmaf(cx, cx, fmaf(cy, cy, cz * cz)));
  }
}

__global__ __launch_bounds__(1024) void knnfeat_kernel(const float4* __restrict__ cpack,
                                                       const float* __restrict__ projc,
                                                       const float* __restrict__ projn,
                                                       const float* __restrict__ w,
                                                       const float* __restrict__ gamma,
                                                       const float* __restrict__ beta,
                                                       const float* __restrict__ mean,
                                                       const float* __restrict__ var,
                                                       float* __restrict__ out) {
  __shared__ float4 pA[NPTS / 2];         // 64 KB: (x0,x1,y0,y1) per pair
  __shared__ float4 pB[NPTS / 2];         // 64 KB: (z0,z1,w0,w1) per pair
  __shared__ int lidx[KWAVES][QW][CAPC];  // 16 KB; reused as zbuf (per-wave rows)
  __shared__ int nsel[KWAVES][QW][KNN];   // 5 KB
  int tid = threadIdx.x;
  int lane = tid & 63;
  int wq = tid >> 6;            // wave 0..15
  int blk = blockIdx.x;         // 256 blocks (1 per CU)
  int bb = blk >> 7;            // batch
  int q0 = blk * QB + wq * QW;  // this wave's 4 queries
  const float4* cb = cpack + bb * NPTS;

  // stage candidates in pair-SoA layout (coalesced: 2 dwordx4 per thread/iter)
  for (int j = tid; j < NPTS / 2; j += 1024) {
    float4 c0 = cb[2 * j], c1 = cb[2 * j + 1];
    pA[j] = make_float4(c0.x, c1.x, c0.y, c1.y);
    pB[j] = make_float4(c0.z, c1.z, c0.w, c1.w);
  }
  float qx[QW], qy[QW], qz[QW];
  v2f m2x[QW], m2y[QW], m2z[QW];
#pragma unroll
  for (int qi = 0; qi < QW; ++qi) {
    float4 qp = cpack[q0 + qi];
    qx[qi] = qp.x; qy[qi] = qp.y; qz[qi] = qp.z;
    float ax = -2.f * qp.x, ay = -2.f * qp.y, az = -2.f * qp.z;
    m2x[qi] = (v2f){ax, ax}; m2y[qi] = (v2f){ay, ay}; m2z[qi] = (v2f){az, az};
  }
  __syncthreads();

  // ---- pass 1: per-lane bin minima of d~ (64 pairs = 128 candidates/lane)
  float m[QW];
#pragma unroll
  for (int qi = 0; qi < QW; ++qi) m[qi] = 3.0e38f;
#pragma unroll 4
  for (int i = 0; i < NPTS / 128; ++i) {
    float4 A = pA[lane + i * 64];
    float4 Bv = pB[lane + i * 64];
#pragma unroll
    for (int qi = 0; qi < QW; ++qi) {
      v2f d = dtilde2(m2x[qi], m2y[qi], m2z[qi], A, Bv);
      m[qi] = fminf(m[qi], fminf(d.x, d.y));
    }
  }
  // tau >= 20th-smallest lane-min (>= global d~_(20)) via float bisection.
  // Invariant: count(m <= hi) >= KNN. |d~| <= |c|^2+2|q||c| < 100 << 256.
  float lo[QW], hi[QW];
#pragma unroll
  for (int qi = 0; qi < QW; ++qi) { lo[qi] = -256.f; hi[qi] = 256.f; }
#pragma unroll 1
  for (int it = 0; it < 24; ++it) {
#pragma unroll
    for (int qi = 0; qi < QW; ++qi) {
      float mid = (lo[qi] + hi[qi]) * 0.5f;
      int c = (int)__popcll(__ballot(m[qi] <= mid));
      if (c >= KNN) hi[qi] = mid; else lo[qi] = mid;
    }
  }

  // ---- pass 2: ballot-compact candidates with d~ <= tau (~24 expected/query)
  int cnt[QW];
#pragma unroll
  for (int qi = 0; qi < QW; ++qi) cnt[qi] = 0;
  unsigned long long lmlt = (1ull << lane) - 1ull;
#pragma unroll 2
  for (int i = 0; i < NPTS / 128; ++i) {
    float4 A = pA[lane + i * 64];
    float4 Bv = pB[lane + i * 64];
#pragma unroll
    for (int qi = 0; qi < QW; ++qi) {
      v2f d = dtilde2(m2x[qi], m2y[qi], m2z[qi], A, Bv);
      bool pr = fminf(d.x, d.y) <= hi[qi];
      unsigned long long mk = __ballot(pr);
      if (mk) { // rare: P ~ 0.3 per pair-iter per query
        bool p0 = d.x <= hi[qi], p1 = d.y <= hi[qi];
        unsigned long long b0 = __ballot(p0);
        unsigned long long b1 = __ballot(p1);
        int c0 = (int)__popcll(b0);
        int ofs0 = cnt[qi] + (int)__popcll(b0 & lmlt);
        int ofs1 = cnt[qi] + c0 + (int)__popcll(b1 & lmlt);
        int base2 = 2 * (lane + i * 64);
        if (p0 && ofs0 < CAPC) lidx[wq][qi][ofs0] = base2;
        if (p1 && ofs1 < CAPC) lidx[wq][qi][ofs1] = base2 + 1;
        cnt[qi] += c0 + (int)__popcll(b1);
      }
    }
  }

  // ---- exact fp64 rank select: one candidate per lane, readlane broadcast
  double dd[QW]; int ii[QW]; int cC[QW];
#pragma unroll
  for (int qi = 0; qi < QW; ++qi) {
    cC[qi] = min(cnt[qi], CAPC);
    dd[qi] = 1e300; ii[qi] = -1;
    if (lane < cC[qi]) {
      int id = lidx[wq][qi][lane];
      int pj = id >> 1, ph = id & 1;
      float4 A = pA[pj], Bv = pB[pj];
      float cx = ph ? A.y : A.x;
      float cy = ph ? A.w : A.z;
      float cz = ph ? Bv.y : Bv.x;
      dd[qi] = d2d(qx[qi], qy[qi], qz[qi], cx, cy, cz);
      ii[qi] = id;
    }
  }
#pragma unroll
  for (int qi = 0; qi < QW; ++qi) {
    int xlo = __double2loint(dd[qi]), xhi = __double2hiint(dd[qi]);
    int r = 0;
#pragma unroll 1
    for (int j = 0; j < cC[qi]; ++j) {
      double dj = __hiloint2double(__builtin_amdgcn_readlane(xhi, j),
                                   __builtin_amdgcn_readlane(xlo, j));
      int idj = __builtin_amdgcn_readlane(ii[qi], j);
      r += (dj < dd[qi]) || (dj == dd[qi] && idj < ii[qi]);
    }
    if (ii[qi] >= 0 && r < KNN) nsel[wq][qi][r] = ii[qi];
  }

  // ---- fused feature + conv + BN/leaky + max-over-k epilogue
  float* zbuf = (float*)&lidx[0][0][0]; // per-wave region == own dead lidx rows
  float wd  = w[lane * EDIM + 192];
  float wld = w[lane * EDIM + 193];
  float wrh = w[lane * EDIM + 194];
  float wdv = w[lane * EDIM + 195];
  float wa  = w[lane * EDIM + 196];
  float sc = gamma[lane] / sqrtf(var[lane] + 1e-5f);
  float muv = mean[lane], bt = beta[lane];
#pragma unroll 2
  for (int qi = 0; qi < QW; ++qi) {
    int gq = q0 + qi;
    int jj = nsel[wq][qi][lane < KNN ? lane : 0] & (NPTS - 1);
    int pj = jj >> 1, ph = jj & 1;
    float4 A = pA[pj], Bv = pB[pj];
    float nx = ph ? A.y : A.x;
    float ny = ph ? A.w : A.z;
    float nz = ph ? Bv.y : Bv.x;
    float vx = nx - qx[qi], vy = ny - qy[qi], vz = nz - qz[qi];
    float dist = sqrtf(fmaf(vx, vx, fmaf(vy, vy, vz * vz)));
    float inv = 1.f / (dist + 1e-6f);
    float vnx = vx * inv, vny = vy * inv, vnz = vz * inv;
    float msk = (lane < KNN) ? 1.f : 0.f;
    float sd = wsum(dist * msk);
    float szn = wsum(nz * msk);
    float sx = wsum(vnx * msk);
    float sy = wsum(vny * msk);
    float s3 = wsum(vnz * msk);
    float ld = sd * (1.f / KNN);
    float rh = qz[qi] - szn * (1.f / KNN);
    float dev = dist - ld;
    float dvs = wsum(dev * dev * msk);
    float dv = dvs * (1.f / (KNN - 1));
    float mdx = sx * (1.f / KNN), mdy = sy * (1.f / KNN), mdz = s3 * (1.f / KNN);
    float mnorm = sqrtf(fmaf(mdx, mdx, fmaf(mdy, mdy, mdz * mdz)));
    float rinv = 1.f / (mnorm + 1e-6f);
    mdx *= rinv; mdy *= rinv; mdz *= rinv;
    float cosv = vnx * mdx + vny * mdy + vnz * mdz;
    float angle = 1.f - fabsf(cosv);
    float base = projc[(size_t)gq * 64 + lane] + ld * wld + rh * wrh + dv * wdv;
    float zmax = -3.0e38f, zmin = 3.0e38f;
#pragma unroll
    for (int kk = 0; kk < KNN; ++kk) {
      float dk = bcastf(dist, kk);
      float ak = bcastf(angle, kk);
      int jk = __builtin_amdgcn_readlane(jj, kk);
      float z = base + projn[(size_t)(bb * NPTS + jk) * 64 + lane] + dk * wd + ak * wa;
      zmax = fmaxf(zmax, z);
      zmin = fminf(zmin, z);
    }
    float M = (sc >= 0.f) ? zmax : zmin; // BN scale sign-aware (monotone epilogue)
    float yv = (M - muv) * sc + bt;
    yv = (yv >= 0.f) ? yv : 0.2f * yv;
    int qcol = wq * QW + qi;
    zbuf[qcol * 64 + ((lane + qcol) & 63)] = yv; // swizzled: conflict-free both ways
  }
  __syncthreads();
  // cooperative transpose writeout: out[b][o][n0..n0+63]
  {
    int o = tid >> 4, g = tid & 15;
    int n0 = (blk & 127) * 64;
    int q4 = g * 4;
    float4 v;
    v.x = zbuf[(q4 + 0) * 64 + ((o + q4 + 0) & 63)];
    v.y = zbuf[(q4 + 1) * 64 + ((o + q4 + 1) & 63)];
    v.z = zbuf[(q4 + 2) * 64 + ((o + q4 + 2) & 63)];
    v.w = zbuf[(q4 + 3) * 64 + ((o + q4 + 3) & 63)];
    *(float4*)(out + (size_t)bb * CH * NPTS + (size_t)o * NPTS + n0 + q4) = v;
  }
}

extern "C" void kernel_launch(void* const* d_in, const int* in_sizes, int n_in,
                              void* d_out, int out_size, void* d_ws, size_t ws_size,
                              hipStream_t stream) {
  const float* x = (const float*)d_in[0];
  const float* w = (const float*)d_in[1];
  const float* gamma = (const float*)d_in[2];
  const float* beta = (const float*)d_in[3];
  const float* mean = (const float*)d_in[4];
  const float* var = (const float*)d_in[5];
  float* out = (float*)d_out;

  // workspace layout
  const size_t OFF_CPACK = 0;                 // 262144 B
  const size_t OFF_PROJC = 262144;            // 4 MiB
  const size_t OFF_PROJN = 262144 + 4194304;  // 4 MiB
  const size_t NEED = 262144 + 8388608;
  if (ws_size < NEED) return;

  char* ws = (char*)d_ws;
  float4* cpack = (float4*)(ws + OFF_CPACK);
  float* projc = (float*)(ws + OFF_PROJC);
  float* projn = (float*)(ws + OFF_PROJN);

  proj_kernel<<<dim3(64, 8), 256, 0, stream>>>(x, w, cpack, projc, projn);
  knnfeat_kernel<<<256, 1024, 0, stream>>>(cpack, projc, projn, w,
                                           gamma, beta, mean, var, out);
}

// Round 8
// 79.472 us; speedup vs baseline: 1.4007x; 1.1921x over previous
//
#include <hip/hip_runtime.h>

// EdgeConv (B=2, N=8192, C=64, K=20, OUT=64):
//  proj    -> per-point 64->64 projections (8-way split over mat x out-quarter;
//             builds combined weights (w1-w2),(w2+w3) in LDS from w directly;
//             by==0 blocks also pack cpack = (x,y,z,|c|^2))
//  knnfeat -> fused, 1024 threads (16 waves x 4 queries; 4 waves/SIMD and
//             ~16 VALU ops per ds_read_b128 -- the verified balance point;
//             both QW=8@512thr (r6) and pk_fma@halved-ops (r7) regressed).
//             pass1: lane bin-minima of d~ = |c|^2 - 2 q.c (3 fma) ->
//                    tau >= d~_(20) via 24-step float bisection (ballot count)
//             pass2: ballot-compact (<=64) candidates with d~ <= tau
//             exact fp64 rank select (readlane broadcast, ties -> lower idx)
//             feat: edge features + gathered projections + BN/leaky/max,
//                   swizzled LDS transpose stage -> coalesced float4 out.

#define NPTS 8192
#define NBATCH 2
#define NQ (NBATCH * NPTS)
#define CH 64
#define KNN 20
#define EDIM 197
#define QW 4             // queries per wave
#define KWAVES 16        // waves per block (1024 threads)
#define QB (QW * KWAVES) // 64 queries per block
#define CAPC 64          // collected-candidate capacity (mean ~24)

__device__ __forceinline__ float wsum(float v) {
  v += __shfl_xor(v, 1, 64);
  v += __shfl_xor(v, 2, 64);
  v += __shfl_xor(v, 4, 64);
  v += __shfl_xor(v, 8, 64);
  v += __shfl_xor(v, 16, 64);
  v += __shfl_xor(v, 32, 64);
  return v;
}

// monotone-shifted distance surrogate: d~ = |c|^2 - 2 q.c  (= d^2 - |q|^2 exact)
// identical fmaf chain in both passes -> bitwise-consistent
__device__ __forceinline__ float dtilde(float m2x, float m2y, float m2z, float4 c) {
  return fmaf(m2x, c.x, fmaf(m2y, c.y, fmaf(m2z, c.z, c.w)));
}

// exact-enough fp64 true distance (fp32 diffs exact in fp64, squares exact)
__device__ __forceinline__ double d2d(float qx, float qy, float qz, float4 c) {
  double dx = (double)qx - (double)c.x;
  double dy = (double)qy - (double)c.y;
  double dz = (double)qz - (double)c.z;
  return dx * dx + dy * dy + dz * dz;
}

__device__ __forceinline__ float bcastf(float v, int l) {
  return __int_as_float(__builtin_amdgcn_readlane(__float_as_int(v), l));
}

// blockIdx.y in [0,8): mat = by>>2, output-quarter = by&3 (16 channels each).
// by==0 blocks additionally pack cpack (xyz + |c|^2).
__global__ __launch_bounds__(256) void proj_kernel(const float* __restrict__ x,
                                                   const float* __restrict__ w,
                                                   float4* __restrict__ cpack,
                                                   float* __restrict__ projc,
                                                   float* __restrict__ projn) {
  __shared__ float wl[CH * 16];
  int by = blockIdx.y;
  int mat = by >> 2, oq = by & 3;
  for (int i = threadIdx.x; i < CH * 16; i += 256) {
    int c = i >> 4, oo = i & 15;
    int o = oq * 16 + oo;
    float w1 = w[o * EDIM + c];
    float w2 = w[o * EDIM + 64 + c];
    float w3 = w[o * EDIM + 128 + c];
    wl[i] = mat ? (w2 + w3) : (w1 - w2);
  }
  __syncthreads();
  int p = blockIdx.x * 256 + threadIdx.x;
  int b = p >> 13, n = p & (NPTS - 1);
  const float* xb = x + (size_t)b * CH * NPTS + n;
  float acc[16];
#pragma unroll
  for (int o = 0; o < 16; ++o) acc[o] = 0.f;
#pragma unroll 4
  for (int c = 0; c < CH; ++c) {
    float xv = xb[(size_t)c * NPTS]; // coalesced across threads
    const float4* wr = (const float4*)(wl + c * 16); // uniform -> broadcast
#pragma unroll
    for (int o4 = 0; o4 < 4; ++o4) {
      float4 wv = wr[o4];
      acc[o4 * 4 + 0] = fmaf(wv.x, xv, acc[o4 * 4 + 0]);
      acc[o4 * 4 + 1] = fmaf(wv.y, xv, acc[o4 * 4 + 1]);
      acc[o4 * 4 + 2] = fmaf(wv.z, xv, acc[o4 * 4 + 2]);
      acc[o4 * 4 + 3] = fmaf(wv.w, xv, acc[o4 * 4 + 3]);
    }
  }
  float* dst = (mat ? projn : projc) + (size_t)p * 64 + oq * 16;
#pragma unroll
  for (int o4 = 0; o4 < 4; ++o4)
    ((float4*)dst)[o4] = make_float4(acc[o4 * 4 + 0], acc[o4 * 4 + 1],
                                     acc[o4 * 4 + 2], acc[o4 * 4 + 3]);
  if (by == 0) {
    float cx = xb[0], cy = xb[(size_t)NPTS], cz = xb[(size_t)2 * NPTS];
    cpack[p] = make_float4(cx, cy, cz, fmaf(cx, cx, fmaf(cy, cy, cz * cz)));
  }
}

__global__ __launch_bounds__(1024) void knnfeat_kernel(const float4* __restrict__ cpack,
                                                       const float* __restrict__ projc,
                                                       const float* __restrict__ projn,
                                                       const float* __restrict__ w,
                                                       const float* __restrict__ gamma,
                                                       const float* __restrict__ beta,
                                                       const float* __restrict__ mean,
                                                       const float* __restrict__ var,
                                                       float* __restrict__ out) {
  __shared__ float4 t4[NPTS];             // 128 KB, live for whole kernel
  __shared__ int lidx[KWAVES][QW][CAPC];  // 16 KB; reused as zbuf (per-wave rows)
  __shared__ int nsel[KWAVES][QW][KNN];   // 5 KB
  int tid = threadIdx.x;
  int lane = tid & 63;
  int wq = tid >> 6;            // wave 0..15
  int blk = blockIdx.x;         // 256 blocks (1 per CU)
  int bb = blk >> 7;            // batch
  int q0 = blk * QB + wq * QW;  // this wave's 4 queries
  const float4* cb = cpack + bb * NPTS;

  for (int i = tid; i < NPTS; i += 1024) t4[i] = cb[i];
  float qx[QW], qy[QW], qz[QW], m2x[QW], m2y[QW], m2z[QW];
#pragma unroll
  for (int qi = 0; qi < QW; ++qi) {
    float4 qp = cpack[q0 + qi];
    qx[qi] = qp.x; qy[qi] = qp.y; qz[qi] = qp.z;
    m2x[qi] = -2.f * qp.x; m2y[qi] = -2.f * qp.y; m2z[qi] = -2.f * qp.z;
  }
  __syncthreads();

  // ---- pass 1: per-lane bin minima of d~ (128 candidates per lane)
  float m[QW];
#pragma unroll
  for (int qi = 0; qi < QW; ++qi) m[qi] = 3.0e38f;
#pragma unroll 2
  for (int i = 0; i < NPTS / 64; ++i) {
    float4 c = t4[lane + i * 64];
#pragma unroll
    for (int qi = 0; qi < QW; ++qi)
      m[qi] = fminf(m[qi], dtilde(m2x[qi], m2y[qi], m2z[qi], c));
  }
  // tau >= 20th-smallest lane-min (>= global d~_(20)) via float bisection.
  // Invariant: count(m <= hi) >= KNN. |d~| <= |c|^2+2|q||c| < 100 << 256.
  float lo[QW], hi[QW];
#pragma unroll
  for (int qi = 0; qi < QW; ++qi) { lo[qi] = -256.f; hi[qi] = 256.f; }
#pragma unroll 1
  for (int it = 0; it < 24; ++it) {
#pragma unroll
    for (int qi = 0; qi < QW; ++qi) {
      float mid = (lo[qi] + hi[qi]) * 0.5f;
      int c = (int)__popcll(__ballot(m[qi] <= mid));
      if (c >= KNN) hi[qi] = mid; else lo[qi] = mid;
    }
  }

  // ---- pass 2: ballot-compact candidates with d~ <= tau (~24 expected/query)
  int cnt[QW];
#pragma unroll
  for (int qi = 0; qi < QW; ++qi) cnt[qi] = 0;
  unsigned long long lmlt = (1ull << lane) - 1ull;
#pragma unroll 2
  for (int i = 0; i < NPTS / 64; ++i) {
    float4 c = t4[lane + i * 64];
#pragma unroll
    for (int qi = 0; qi < QW; ++qi) {
      bool pr = dtilde(m2x[qi], m2y[qi], m2z[qi], c) <= hi[qi];
      unsigned long long mk = __ballot(pr);
      if (mk) { // skipped ~83% of (iter,query) pairs
        int ofs = cnt[qi] + (int)__popcll(mk & lmlt);
        if (pr && ofs < CAPC) lidx[wq][qi][ofs] = lane + i * 64;
        cnt[qi] += (int)__popcll(mk);
      }
    }
  }

  // ---- exact fp64 rank select: one candidate per lane, readlane broadcast
  double dd[QW]; int ii[QW]; int cC[QW];
#pragma unroll
  for (int qi = 0; qi < QW; ++qi) {
    cC[qi] = min(cnt[qi], CAPC);
    dd[qi] = 1e300; ii[qi] = -1;
    if (lane < cC[qi]) {
      int id = lidx[wq][qi][lane];
      dd[qi] = d2d(qx[qi], qy[qi], qz[qi], t4[id]);
      ii[qi] = id;
    }
  }
#pragma unroll
  for (int qi = 0; qi < QW; ++qi) {
    int xlo = __double2loint(dd[qi]), xhi = __double2hiint(dd[qi]);
    int r = 0;
#pragma unroll 1
    for (int j = 0; j < cC[qi]; ++j) {
      double dj = __hiloint2double(__builtin_amdgcn_readlane(xhi, j),
                                   __builtin_amdgcn_readlane(xlo, j));
      int idj = __builtin_amdgcn_readlane(ii[qi], j);
      r += (dj < dd[qi]) || (dj == dd[qi] && idj < ii[qi]);
    }
    if (ii[qi] >= 0 && r < KNN) nsel[wq][qi][r] = ii[qi];
  }

  // ---- fused feature + conv + BN/leaky + max-over-k epilogue
  float* zbuf = (float*)&lidx[0][0][0]; // per-wave region == own dead lidx rows
  float wd  = w[lane * EDIM + 192];
  float wld = w[lane * EDIM + 193];
  float wrh = w[lane * EDIM + 194];
  float wdv = w[lane * EDIM + 195];
  float wa  = w[lane * EDIM + 196];
  float sc = gamma[lane] / sqrtf(var[lane] + 1e-5f);
  float muv = mean[lane], bt = beta[lane];
#pragma unroll 2
  for (int qi = 0; qi < QW; ++qi) {
    int gq = q0 + qi;
    int jj = nsel[wq][qi][lane < KNN ? lane : 0] & (NPTS - 1);
    float4 nb = t4[jj];
    float vx = nb.x - qx[qi], vy = nb.y - qy[qi], vz = nb.z - qz[qi];
    float dist = sqrtf(fmaf(vx, vx, fmaf(vy, vy, vz * vz)));
    float inv = 1.f / (dist + 1e-6f);
    float vnx = vx * inv, vny = vy * inv, vnz = vz * inv;
    float msk = (lane < KNN) ? 1.f : 0.f;
    float sd = wsum(dist * msk);
    float szn = wsum(nb.z * msk);
    float sx = wsum(vnx * msk);
    float sy = wsum(vny * msk);
    float s3 = wsum(vnz * msk);
    float ld = sd * (1.f / KNN);
    float rh = qz[qi] - szn * (1.f / KNN);
    float dev = dist - ld;
    float dvs = wsum(dev * dev * msk);
    float dv = dvs * (1.f / (KNN - 1));
    float mdx = sx * (1.f / KNN), mdy = sy * (1.f / KNN), mdz = s3 * (1.f / KNN);
    float mnorm = sqrtf(fmaf(mdx, mdx, fmaf(mdy, mdy, mdz * mdz)));
    float rinv = 1.f / (mnorm + 1e-6f);
    mdx *= rinv; mdy *= rinv; mdz *= rinv;
    float cosv = vnx * mdx + vny * mdy + vnz * mdz;
    float angle = 1.f - fabsf(cosv);
    float base = projc[(size_t)gq * 64 + lane] + ld * wld + rh * wrh + dv * wdv;
    float zmax = -3.0e38f, zmin = 3.0e38f;
#pragma unroll
    for (int kk = 0; kk < KNN; ++kk) {
      float dk = bcastf(dist, kk);
      float ak = bcastf(angle, kk);
      int jk = __builtin_amdgcn_readlane(jj, kk);
      float z = base + projn[(size_t)(bb * NPTS + jk) * 64 + lane] + dk * wd + ak * wa;
      zmax = fmaxf(zmax, z);
      zmin = fminf(zmin, z);
    }
    float M = (sc >= 0.f) ? zmax : zmin; // BN scale sign-aware (monotone epilogue)
    float yv = (M - muv) * sc + bt;
    yv = (yv >= 0.f) ? yv : 0.2f * yv;
    int qcol = wq * QW + qi;
    zbuf[qcol * 64 + ((lane + qcol) & 63)] = yv; // swizzled: conflict-free both ways
  }
  __syncthreads();
  // cooperative transpose writeout: out[b][o][n0..n0+63]
  {
    int o = tid >> 4, g = tid & 15;
    int n0 = (blk & 127) * 64;
    int q4 = g * 4;
    float4 v;
    v.x = zbuf[(q4 + 0) * 64 + ((o + q4 + 0) & 63)];
    v.y = zbuf[(q4 + 1) * 64 + ((o + q4 + 1) & 63)];
    v.z = zbuf[(q4 + 2) * 64 + ((o + q4 + 2) & 63)];
    v.w = zbuf[(q4 + 3) * 64 + ((o + q4 + 3) & 63)];
    *(float4*)(out + (size_t)bb * CH * NPTS + (size_t)o * NPTS + n0 + q4) = v;
  }
}

extern "C" void kernel_launch(void* const* d_in, const int* in_sizes, int n_in,
                              void* d_out, int out_size, void* d_ws, size_t ws_size,
                              hipStream_t stream) {
  const float* x = (const float*)d_in[0];
  const float* w = (const float*)d_in[1];
  const float* gamma = (const float*)d_in[2];
  const float* beta = (const float*)d_in[3];
  const float* mean = (const float*)d_in[4];
  const float* var = (const float*)d_in[5];
  float* out = (float*)d_out;

  // workspace layout
  const size_t OFF_CPACK = 0;                 // 262144 B
  const size_t OFF_PROJC = 262144;            // 4 MiB
  const size_t OFF_PROJN = 262144 + 4194304;  // 4 MiB
  const size_t NEED = 262144 + 8388608;
  if (ws_size < NEED) return;

  char* ws = (char*)d_ws;
  float4* cpack = (float4*)(ws + OFF_CPACK);
  float* projc = (float*)(ws + OFF_PROJC);
  float* projn = (float*)(ws + OFF_PROJN);

  proj_kernel<<<dim3(64, 8), 256, 0, stream>>>(x, w, cpack, projc, projn);
  knnfeat_kernel<<<256, 1024, 0, stream>>>(cpack, projc, projn, w,
                                           gamma, beta, mean, var, out);
}